// Round 9
// baseline (452.374 us; speedup 1.0000x reference)
//
#include <hip/hip_runtime.h>

#define EPSB 1e-5f
#define NEG 0.2f

__device__ __forceinline__ float lrelu(float y) { return y >= 0.f ? y : NEG * y; }

// async global->LDS 16B/lane (wave-uniform LDS dest, per-lane global src)
typedef const __attribute__((address_space(1))) unsigned int gas1_u32;
typedef __attribute__((address_space(3))) unsigned int as3_u32;
__device__ __forceinline__ void gload16(const float* g, float* l) {
  __builtin_amdgcn_global_load_lds((gas1_u32*)g, (as3_u32*)l, 16, 0, 0);
}
#define WAITVM(N) asm volatile("s_waitcnt vmcnt(" #N ")" ::: "memory")

// barrier that does NOT drain vmcnt (keeps global prefetches in flight);
// lgkmcnt(0) gives LDS store/load visibility, s_barrier syncs the block.
__device__ __forceinline__ void barrier_nodrain() {
  asm volatile("s_waitcnt lgkmcnt(0)" ::: "memory");
  __builtin_amdgcn_s_barrier();
  __builtin_amdgcn_sched_barrier(0);
}

// ---------------------------------------------------------------------------
// Fused conv frontend (unchanged, validated): output xt[p][b][s].
// ---------------------------------------------------------------------------
__global__ __launch_bounds__(256) void k_front(
    const float* __restrict__ data, const float* __restrict__ w1,
    const float* __restrict__ w2, const float* __restrict__ w3,
    const float* __restrict__ lw, const float* __restrict__ bg,
    const float* __restrict__ bb, const float* __restrict__ bm,
    const float* __restrict__ bv, float* __restrict__ xt)
{
  __shared__ float x1s[32][132];
  __shared__ float x2s[32][40];
  __shared__ float x3s[32][20];
  const int b = blockIdx.x >> 3, q = blockIdx.x & 7, t = threadIdx.x;
  const int o1s = (937*q)/8, o1e = (937*(q+1))/8;
  const int o2s = (234*q)/8, o2e = (234*(q+1))/8;
  const int o3s = (116*q)/8, o3e = (116*(q+1))/8;
  int n2s = min(o2s, 2*o3s);
  int n2e = max(o2e, 2*(o3e-1)+4); if (n2e > 234) n2e = 234;
  int n1s = min(o1s, 4*n2s);
  int n1e = max(o1e, 4*(n2e-1)+5); if (n1e > 937) n1e = 937;
  const int w1w = n1e - n1s, w2w = n2e - n2s, w3w = o3e - o3s;

  for (int idx = t; idx < 32*w1w; idx += 256) {
    int c = idx / w1w, j = n1s + idx % w1w;
    float acc = 0.f;
    int base = 5*j - 2;
    #pragma unroll
    for (int k = 0; k < 5; ++k) {
      int pos = base + k;
      float d = (pos >= 0 && pos < 4681) ? data[b*4681 + pos] : 0.f;
      acc += w1[c*5 + k] * d;
    }
    float sc = bg[c] * rsqrtf(bv[c] + EPSB);
    x1s[c][j - n1s] = lrelu((acc - bm[c]) * sc + bb[c]);
  }
  __syncthreads();
  for (int idx = t; idx < 32*w2w; idx += 256) {
    int c = idx / w2w, j = n2s + idx % w2w;
    float acc = 0.f;
    int col = 4*j - n1s;
    for (int ci = 0; ci < 32; ++ci) {
      #pragma unroll
      for (int k = 0; k < 5; ++k) acc += w2[(c*32 + ci)*5 + k] * x1s[ci][col + k];
    }
    float sc = bg[32+c] * rsqrtf(bv[32+c] + EPSB);
    x2s[c][j - n2s] = lrelu((acc - bm[32+c]) * sc + bb[32+c]);
  }
  __syncthreads();
  for (int idx = t; idx < 32*w3w; idx += 256) {
    int c = idx / w3w, j = o3s + idx % w3w;
    float acc = 0.f;
    int col = 2*j - n2s;
    for (int ci = 0; ci < 32; ++ci) {
      #pragma unroll
      for (int k = 0; k < 4; ++k) acc += w3[(c*32 + ci)*4 + k] * x2s[ci][col + k];
    }
    float sc = bg[64+c] * rsqrtf(bv[64+c] + EPSB);
    x3s[c][j - o3s] = lrelu((acc - bm[64+c]) * sc + bb[64+c]);
  }
  __syncthreads();
  const int np1 = o1e - o1s, np2 = o2e - o2s, np3 = o3e - o3s;
  const int np = np1 + np2 + np3;
  for (int idx = t; idx < np*32; idx += 256) {
    int pi = idx >> 5, s = idx & 31;
    float acc = 0.f;
    int p;
    if (pi < np1) {
      int j = o1s + pi; p = j;
      int col = j - n1s;
      for (int ci = 0; ci < 32; ++ci) acc += lw[s*32 + ci] * x1s[ci][col];
    } else if (pi < np1 + np2) {
      int j = o2s + (pi - np1); p = 937 + j;
      int col = j - n2s;
      for (int ci = 0; ci < 32; ++ci) acc += lw[s*32 + ci] * x2s[ci][col];
    } else {
      int j = o3s + (pi - np1 - np2); p = 1171 + j;
      int col = j - o3s;
      for (int ci = 0; ci < 32; ++ci) acc += lw[s*32 + ci] * x3s[ci][col];
    }
    float sc = bg[96+s] * rsqrtf(bv[96+s] + EPSB);
    xt[p*1024 + b*32 + s] = lrelu((acc - bm[96+s]) * sc + bb[96+s]);
  }
}

// ---------------------------------------------------------------------------
// Pass A: EXACT R4 version (best measured: 193 us). u stride 1287.
// ---------------------------------------------------------------------------
__global__ __launch_bounds__(256) void k_uhat(
    const float* __restrict__ W, const float* __restrict__ xt,
    float* __restrict__ u, float* __restrict__ s0part)
{
  extern __shared__ float lds[];
  float* xs = lds;                       // [8 p][32 b][32 s] swizzled
  float* wbuf = lds + 8192;              // [4 waves][2][1280]
  const int t = threadIdx.x;
  const int wi = blockIdx.x*4 + (t >> 6);
  const int lane = t & 63;
  const int l = wi % 40, chunk = wi / 40;
  const int vg = lane >> 3, bg = lane & 7;
  const int p0 = chunk * 8;
  float* myw = wbuf + (t >> 6) * 2560;
  const float* Wl = W + (size_t)l * 1287 * 1280;

  for (int g = t; g < 2048; g += 256) {
    int pl = g >> 8, rem = g & 255;
    int b = rem >> 3, s4 = rem & 7;
    int pg = p0 + pl;
    float4 v = make_float4(0.f, 0.f, 0.f, 0.f);
    if (pg < 1287) v = *(const float4*)(xt + pg*1024 + b*32 + s4*4);
    *(float4*)(xs + pl*1024 + b*32 + ((s4 ^ (b >> 2)) << 2)) = v;
  }
  {
    #pragma unroll
    for (int i = 0; i < 5; ++i) {
      int g = i*64 + lane, v = g >> 3, s4 = (g & 7) ^ (v & 7);
      gload16(Wl + (size_t)p0*1280 + (v*8 + s4)*4, myw + i*256);
    }
    if (p0 + 1 < 1287) {
      #pragma unroll
      for (int i = 0; i < 5; ++i) {
        int g = i*64 + lane, v = g >> 3, s4 = (g & 7) ^ (v & 7);
        gload16(Wl + (size_t)(p0+1)*1280 + (v*8 + s4)*4, myw + 1280 + i*256);
      }
    }
  }
  __syncthreads();

  float s0acc[5][4] = {};
  int cur = 0;
  for (int pp = 0; pp < 8; ++pp) {
    int p = p0 + pp;
    if (p >= 1287) break;
    asm volatile("s_waitcnt lgkmcnt(0)" ::: "memory");
    WAITVM(5);
    const float* wb = myw + cur*1280;
    const float* xp = xs + pp*1024;
    float acc[5][4] = {};
    #pragma unroll
    for (int s4 = 0; s4 < 8; ++s4) {
      float4 wv[5], xv[4];
      #pragma unroll
      for (int i = 0; i < 5; ++i) {
        int v = vg*5 + i;
        wv[i] = *(const float4*)(wb + v*32 + ((s4 ^ (v & 7)) << 2));
      }
      #pragma unroll
      for (int j = 0; j < 4; ++j) {
        int b = bg*4 + j;
        xv[j] = *(const float4*)(xp + b*32 + ((s4 ^ (b >> 2)) << 2));
      }
      #pragma unroll
      for (int i = 0; i < 5; ++i)
        #pragma unroll
        for (int j = 0; j < 4; ++j)
          acc[i][j] += wv[i].x*xv[j].x + wv[i].y*xv[j].y + wv[i].z*xv[j].z + wv[i].w*xv[j].w;
    }
    if (pp < 6 && p + 2 < 1287) {
      asm volatile("s_waitcnt lgkmcnt(0)" ::: "memory");
      #pragma unroll
      for (int i = 0; i < 5; ++i) {
        int g = i*64 + lane, v = g >> 3, s4 = (g & 7) ^ (v & 7);
        gload16(Wl + (size_t)(p+2)*1280 + (v*8 + s4)*4, myw + cur*1280 + i*256);
      }
    }
    float* up = u + ((size_t)(bg*1287 + p))*6400 + l*160;
    #pragma unroll
    for (int i = 0; i < 5; ++i) {
      int v = vg*5 + i;
      *(float4*)(up + v*4) = make_float4(acc[i][0], acc[i][1], acc[i][2], acc[i][3]);
      #pragma unroll
      for (int j = 0; j < 4; ++j) s0acc[i][j] += acc[i][j];
    }
    cur ^= 1;
  }
  float* sp = s0part + (size_t)chunk*51200 + l*1280;
  #pragma unroll
  for (int i = 0; i < 5; ++i) {
    int v = vg*5 + i;
    *(float4*)(sp + v*32 + bg*4) =
        make_float4(s0acc[i][0], s0acc[i][1], s0acc[i][2], s0acc[i][3]);
  }
}

// ---------------------------------------------------------------------------
// squash kernels (unchanged, validated)
// ---------------------------------------------------------------------------
__global__ __launch_bounds__(64) void k_squash0(
    const float* __restrict__ s0, float* __restrict__ v0t)
{
  const int b = blockIdx.x / 40, l = blockIdx.x % 40, t = threadIdx.x;
  float s = 0.f;
  if (t < 40) s = s0[(l*40 + t)*32 + b] * (1.f/40.f);
  float sq = s*s;
  #pragma unroll
  for (int d = 1; d < 64; d <<= 1) sq += __shfl_xor(sq, d);
  float scale = sq > 0.f ? sq / ((1.f + sq) * sqrtf(sq)) : 0.f;
  if (t < 40) v0t[((size_t)(b >> 2)*1600 + l*40 + t)*4 + (b & 3)] = s * scale;
}

__global__ __launch_bounds__(64) void k_squash1(
    const float* __restrict__ sred, float* __restrict__ v1t)
{
  const int b = blockIdx.x / 40, l = blockIdx.x % 40, t = threadIdx.x;
  float s = 0.f;
  size_t off = ((size_t)(b >> 2)*1600 + l*40 + t)*4 + (b & 3);
  if (t < 40) s = sred[off];
  float sq = s*s;
  #pragma unroll
  for (int d = 1; d < 64; d <<= 1) sq += __shfl_xor(sq, d);
  float scale = sq > 0.f ? sq / ((1.f + sq) * sqrtf(sq)) : 0.f;
  if (t < 40) v1t[off] = s * scale;
}

__global__ __launch_bounds__(64) void k_final(
    const float* __restrict__ sred, float* __restrict__ out)
{
  const int b = blockIdx.x / 40, l = blockIdx.x % 40, t = threadIdx.x;
  float s = 0.f;
  if (t < 40) s = sred[((size_t)(b >> 2)*1600 + l*40 + t)*4 + (b & 3)];
  float sq = s*s, ss = s;
  #pragma unroll
  for (int d = 1; d < 64; d <<= 1) { sq += __shfl_xor(sq, d); ss += __shfl_xor(ss, d); }
  float scale = sq > 0.f ? sq / ((1.f + sq) * sqrtf(sq)) : 0.f;
  if (t == 0) out[b*40 + l] = ss * scale;
}

// ---------------------------------------------------------------------------
// k_route4: single-read fused routing with cross-p register pipeline and
// no-vmcnt-drain barriers. Block = (q4, 13 p), 400 thr; t=(l=t/10,vq=t%10).
// Per p (3 barriers):
//   A: dot partial from uu[cur] vs reg vv -> dred; ISSUE loads uu[nxt](p+1)
//      (+ b1g prefetch for pass2) -- they stay in flight across barriers.
//   B: t<160 reduce 10 partials -> dot_lds[b4][40]; b1g store(p1)/add(p2).
//   C: waves 0-3 (one per b4), lane=l: shuffle max/sum softmax -> c_lds[b4][40].
//   D: s4 += uu[cur]*c (u never re-read).
// ---------------------------------------------------------------------------
#define RPC 13
#define NCHUNK 99               // 99*13 = 1287 exactly
__global__ __launch_bounds__(400) void k_route4(
    const float* __restrict__ u, const float* __restrict__ vprev,
    float* __restrict__ b1g, float* __restrict__ spart, int pass)
{
  __shared__ float4 dred[400];
  __shared__ float dot_lds[160];   // [b4][40]
  __shared__ float c_lds[160];     // [b4][40]
  const int q4 = blockIdx.x & 7, chunk = blockIdx.x >> 3;
  const int t = threadIdx.x;            // t = l*10 + vq
  const int l = t / 10;
  const int p0 = chunk * RPC;
  const float4* u4 = (const float4*)u;
  const float4* vp4 = (const float4*)vprev + (size_t)q4*1600;

  float4 vv[4], s4[4], uu[2][4];
  float bprev[2] = {0.f, 0.f};
  #pragma unroll
  for (int j = 0; j < 4; ++j) {
    vv[j] = vp4[t*4 + j];
    s4[j] = make_float4(0.f, 0.f, 0.f, 0.f);
  }
  // prologue: p0 into buffer 0
  {
    const float4* up = u4 + ((size_t)q4*1287 + p0)*1600;
    #pragma unroll
    for (int j = 0; j < 4; ++j) uu[0][j] = up[t*4 + j];
    if (pass == 2 && t < 160) bprev[0] = b1g[((size_t)q4*1287 + p0)*160 + t];
  }

  #pragma unroll 2
  for (int pl = 0; pl < RPC; ++pl) {
    const int cur = pl & 1, nxt = cur ^ 1;
    const size_t qp = (size_t)q4*1287 + p0 + pl;
    // ---- A: dot partial + prefetch p+1
    float4 dp = make_float4(0.f, 0.f, 0.f, 0.f);
    #pragma unroll
    for (int j = 0; j < 4; ++j) {
      dp.x += uu[cur][j].x*vv[j].x; dp.y += uu[cur][j].y*vv[j].y;
      dp.z += uu[cur][j].z*vv[j].z; dp.w += uu[cur][j].w*vv[j].w;
    }
    dred[t] = dp;
    if (pl < RPC-1) {
      const float4* upn = u4 + (qp + 1)*1600;
      #pragma unroll
      for (int j = 0; j < 4; ++j) uu[nxt][j] = upn[t*4 + j];
      if (pass == 2 && t < 160) bprev[nxt] = b1g[(qp + 1)*160 + t];
    }
    barrier_nodrain();
    // ---- B: reduce -> dot_lds[b4][40], b1g io
    if (t < 160) {
      const int lr = t >> 2, b4 = t & 3;
      float d = 0.f;
      #pragma unroll
      for (int vq = 0; vq < 10; ++vq)
        d += ((const float*)&dred[lr*10 + vq])[b4];
      if (pass == 2) d += bprev[cur];
      else           b1g[qp*160 + t] = d;
      dot_lds[b4*40 + lr] = d;
    }
    barrier_nodrain();
    // ---- C: wave-parallel softmax (wave = b4, lane = l)
    if (t < 256) {
      const int b4 = t >> 6, ll = t & 63;
      float d = (ll < 40) ? dot_lds[b4*40 + ll] : -1e30f;
      float m = d;
      #pragma unroll
      for (int off = 32; off; off >>= 1) m = fmaxf(m, __shfl_xor(m, off));
      float e = expf(d - m);          // inactive lanes -> 0
      float Z = e;
      #pragma unroll
      for (int off = 32; off; off >>= 1) Z += __shfl_xor(Z, off);
      if (ll < 40) c_lds[b4*40 + ll] = e * (1.f / Z);
    }
    barrier_nodrain();
    // ---- D: s accumulate from registers
    {
      float c0 = c_lds[l], c1 = c_lds[40 + l], c2 = c_lds[80 + l], c3 = c_lds[120 + l];
      #pragma unroll
      for (int j = 0; j < 4; ++j) {
        s4[j].x += uu[cur][j].x*c0; s4[j].y += uu[cur][j].y*c1;
        s4[j].z += uu[cur][j].z*c2; s4[j].w += uu[cur][j].w*c3;
      }
    }
    // no barrier needed before next A (dred readers finished before bar2;
    // c_lds readers here are fenced by next iteration's bar1+bar2)
  }
  float4* sp = (float4*)(spart + ((size_t)chunk*8 + q4)*6400);
  #pragma unroll
  for (int j = 0; j < 4; ++j) sp[t*4 + j] = s4[j];
}

// sout[w] = sum_{c<n} src[c][w], w < 51200
__global__ __launch_bounds__(256) void k_reduceN(
    const float* __restrict__ src, float* __restrict__ sout, int n)
{
  const int w = blockIdx.x*256 + threadIdx.x;
  float s = 0.f;
  #pragma unroll 4
  for (int c = 0; c < n; ++c) s += src[(size_t)c*51200 + w];
  sout[w] = s;
}

// ---------------------------------------------------------------------------
extern "C" void kernel_launch(void* const* d_in, const int* in_sizes, int n_in,
                              void* d_out, int out_size, void* d_ws, size_t ws_size,
                              hipStream_t stream)
{
  const float* data = (const float*)d_in[0];
  const float* w1   = (const float*)d_in[1];
  const float* w2   = (const float*)d_in[2];
  const float* w3   = (const float*)d_in[3];
  const float* lw   = (const float*)d_in[4];
  const float* bg   = (const float*)d_in[5];
  const float* bb   = (const float*)d_in[6];
  const float* bm   = (const float*)d_in[7];
  const float* bv   = (const float*)d_in[8];
  const float* W    = (const float*)d_in[9];
  float* out = (float*)d_out;

  float* u      = (float*)d_ws;            // 8*1287*6400 = 65,894,400
  float* s0     = u + 65894400;            // 51,200
  float* v0t    = s0 + 51200;              // 51,200
  float* v1t    = v0t + 51200;             // 51,200
  float* s1     = v1t + 51200;             // 51,200
  float* xt     = s1 + 51200;              // 1,317,888
  float* big    = xt + 1317888;
  float* s0part = big;                     // [161][51200] (dead after reduce)
  float* b1g    = big;                     // 1,647,360 (live pass1 -> pass2)
  float* spart  = b1g + 1647360;           // [99][51200] = 5,068,800
  // total ~303 MB

  const int KU_LDS = (8192 + 4*2*1280) * 4;  // 73,728 B
  hipFuncSetAttribute((const void*)k_uhat,
                      hipFuncAttributeMaxDynamicSharedMemorySize, KU_LDS);

  k_front<<<256, 256, 0, stream>>>(data, w1, w2, w3, lw, bg, bb, bm, bv, xt);
  k_uhat<<<1610, 256, KU_LDS, stream>>>(W, xt, u, s0part);
  k_reduceN<<<200, 256, 0, stream>>>(s0part, s0, 161);
  k_squash0<<<1280, 64, 0, stream>>>(s0, v0t);

  k_route4<<<NCHUNK*8, 400, 0, stream>>>(u, v0t, b1g, spart, 1);
  k_reduceN<<<200, 256, 0, stream>>>(spart, s1, NCHUNK);
  k_squash1<<<1280, 64, 0, stream>>>(s1, v1t);

  k_route4<<<NCHUNK*8, 400, 0, stream>>>(u, v1t, b1g, spart, 2);
  k_reduceN<<<200, 256, 0, stream>>>(spart, s0, NCHUNK);
  k_final<<<1280, 64, 0, stream>>>(s0, out);
}